// Round 22
// baseline (28.429 us; speedup 1.0000x reference)
//
#include <hip/hip_runtime.h>

#define N_TOKENS   65536
#define TOKS_PER_BLK 128
#define MAIN_TILES (N_TOKENS / TOKS_PER_BLK + 100)    // 612
#define ORD_SIZE    (MAIN_TILES * TOKS_PER_BLK)       // 78336
#define NB_M2   400
#define NB_G1T  1250
#define NB_HIST 256
#define NCHUNK  256
#define PREP_BLOCKS (NB_M2 + NB_G1T + NB_HIST)        // 1906
#define TOK_MASK 0x1FFFF                               // low 17 bits = token id

// ---- ws layout (float offsets) ----
#define WS_M2T  0                          // 100*4096 bf16 = 204800 floats
#define WS_G1T  204800                     // 10000*32 bf16 = 160000 floats
#define WS_CNT  364800                     // cntT[128][256] ints = 32768
#define WS_ORD  397568                     // ORD_SIZE ints
#define WS_NEED ((size_t)(397568 + ORD_SIZE) * 4)     // ~1.9 MB

typedef __attribute__((ext_vector_type(8))) short bf16x8;
typedef __attribute__((ext_vector_type(4))) float f32x4;

__device__ __forceinline__ unsigned short f2bf(float x) {
    union { float f; unsigned u; } v; v.f = x;
    unsigned r = v.u + 0x7FFF + ((v.u >> 16) & 1);   // RNE
    return (unsigned short)(r >> 16);
}

// ---------------------------------------------------------------------------
// K1 "prep" — M2/G1T roles verbatim r21; hist role: 256 chunks x 256 tokens.
// ---------------------------------------------------------------------------
__global__ __launch_bounds__(256) void prep(
    const int* __restrict__ idx,
    const float* __restrict__ c0, const float* __restrict__ c1,
    const float* __restrict__ c2, const float* __restrict__ c3,
    const float* __restrict__ c4, const float* __restrict__ c5,
    unsigned short* __restrict__ M2T, unsigned short* __restrict__ G1Tb,
    int* __restrict__ cntT) {
    __shared__ float smem[5200];
    const int b = blockIdx.x, t = threadIdx.x;

    if (b < NB_M2) {
        const int i2 = b >> 2;
        const int p  = b & 3;
        float* c4l = smem;
        float* c5l = smem + 1024;
        float* t45 = smem + 1056;
        float* c3p = smem + 1568;
        float* Wl  = smem + 2080;
        float* c2l = smem + 3104;
        *(float4*)(c4l + t * 4) = *(const float4*)(c4 + t * 4);
        if (t < 8) *(float4*)(c5l + t * 4) = *(const float4*)(c5 + t * 4);
        if (t < 128) {
            const int r = t >> 2, q4 = (t & 3) * 4;
            *(float4*)(c3p + r * 16 + q4) = *(const float4*)(c3 + (r * 4 + p) * 16 + q4);
        }
        {
            const int r = t >> 3, s4 = (t & 7) * 4;
            const float4 v = *(const float4*)(c2 + r * 3200 + i2 * 32 + s4);
            c2l[r * 33 + s4 + 0] = v.x;
            c2l[r * 33 + s4 + 1] = v.y;
            c2l[r * 33 + s4 + 2] = v.z;
            c2l[r * 33 + s4 + 3] = v.w;
        }
        __syncthreads();
#pragma unroll
        for (int k = 0; k < 2; ++k) {      // T45[q][u]
            const int e = t + k * 256;
            const int q = e >> 5, u = e & 31;
            const int m1 = u >> 2, v = u & 3;
            float acc = 0.f;
#pragma unroll
            for (int m2 = 0; m2 < 8; ++m2)
                acc = fmaf(c4l[q * 64 + m1 * 8 + m2], c5l[m2 * 4 + v], acc);
            t45[e] = acc;
        }
        __syncthreads();
#pragma unroll
        for (int k = 0; k < 4; ++k) {      // Wl[s][jl]
            const int e = t + k * 256;
            const int s = e >> 5, jl = e & 31;
            float acc = 0.f;
#pragma unroll
            for (int q = 0; q < 16; ++q)
                acc = fmaf(c3p[s * 16 + q], t45[q * 32 + jl], acc);
            Wl[e] = acc;
        }
        __syncthreads();
#pragma unroll
        for (int k = 0; k < 4; ++k) {      // M2T[i2][(p*32+jl)*32+r]
            const int e = t + k * 256;
            const int jl = e >> 5, r = e & 31;
            float acc = 0.f;
#pragma unroll
            for (int s = 0; s < 32; ++s)
                acc = fmaf(c2l[r * 33 + s], Wl[s * 32 + jl], acc);
            M2T[i2 * 4096 + p * 1024 + e] = f2bf(acc);
        }
    } else if (b < NB_M2 + NB_G1T) {
        const int pair = (b - NB_M2) * 8 + (t >> 5);
        const int s = t & 31;
        const int i0 = pair / 100;
        const int i1 = pair - i0 * 100;
        const float4* a4 = (const float4*)(c0 + i0 * 32);
        const float* c1p = c1 + i1 * 32 + s;
        float acc = 0.f;
#pragma unroll
        for (int r4 = 0; r4 < 8; ++r4) {
            const float4 a = a4[r4];
            acc = fmaf(a.x, c1p[(r4 * 4 + 0) * 3200], acc);
            acc = fmaf(a.y, c1p[(r4 * 4 + 1) * 3200], acc);
            acc = fmaf(a.z, c1p[(r4 * 4 + 2) * 3200], acc);
            acc = fmaf(a.w, c1p[(r4 * 4 + 3) * 3200], acc);
        }
        G1Tb[pair * 32 + s] = f2bf(acc);
    } else {
        const int hb = b - (NB_M2 + NB_G1T);     // chunk 0..255 (256 tokens)
        int* lh = (int*)smem;
        if (t < 128) lh[t] = 0;
        __syncthreads();
        atomicAdd(&lh[idx[hb * 256 + t] % 100], 1);
        __syncthreads();
        if (t < 128) cntT[t * NCHUNK + hb] = lh[t];   // transposed store
    }
}

// ---------------------------------------------------------------------------
// K2 "sort2" — 256 blocks x 256 tokens (1/thread); packed (pair<<17)|token
// entries; deterministic padded bucket layout (identical output semantics).
// ---------------------------------------------------------------------------
__global__ __launch_bounds__(256) void sort2(const int* __restrict__ idx,
                                             const int* __restrict__ cntT,
                                             int* __restrict__ order) {
    __shared__ int totals[100];
    __shared__ int offsj[100];
    __shared__ int sb[101];
    __shared__ int lhj[100];
    const int j = blockIdx.x, t = threadIdx.x;
    if (t < 100) {
        lhj[t] = 0;
        const int4* row = (const int4*)(cntT + t * NCHUNK);
        int tot = 0, off = 0;
#pragma unroll
        for (int i = 0; i < NCHUNK / 4; ++i) {
            const int4 v = row[i];
            const int cb = i * 4;
            tot += v.x + v.y + v.z + v.w;
            if (cb + 0 < j) off += v.x;       // j uniform per block
            if (cb + 1 < j) off += v.y;
            if (cb + 2 < j) off += v.z;
            if (cb + 3 < j) off += v.w;
        }
        totals[t] = tot;
        offsj[t] = off;
    }
    __syncthreads();
    if (t < 64) {                          // padded exclusive scan (1 wave)
        const int e0 = 2 * t, e1 = 2 * t + 1;
        const int p0 = (e0 < 100) ? ((totals[e0] + 127) & ~127) : 0;
        const int p1 = (e1 < 100) ? ((totals[e1] + 127) & ~127) : 0;
        const int pair = p0 + p1;
        int incl = pair;
#pragma unroll
        for (int d = 1; d < 64; d <<= 1) {
            const int v = __shfl_up(incl, d, 64);
            if (t >= d) incl += v;
        }
        const int base = incl - pair;
        if (e0 < 100) sb[e0] = base;
        if (e1 < 100) sb[e1] = base + p0;
        if (t == 63) sb[100] = incl;
    }
    __syncthreads();
    {
        const int n = j * 256 + t;
        const int iv = idx[n];
        const int bb = iv % 100;
        const int pkd = ((iv / 100) << 17) | n;   // pack pair + token
        const int rnk = atomicAdd(&lhj[bb], 1);
        order[sb[bb] + offsj[bb] + rnk] = pkd;
    }
    if (j < 100) {                         // pad-fill bucket j
        const int tot = totals[j];
        const int pt = (tot + 127) & ~127;
        for (int i = tot + t; i < pt; i += 256) order[sb[j] + i] = -1;
    }
    {
        const int gt = sb[100];
        for (int i = gt + j * 256 + t; i < ORD_SIZE; i += NCHUNK * 256) order[i] = -1;
    }
}

// ---------------------------------------------------------------------------
// K3 "tt_main" — verbatim r21 (MFMA + NT stores + packed gather).
// ---------------------------------------------------------------------------
__global__ __launch_bounds__(256) void tt_main(
    const int* __restrict__ idx, const int* __restrict__ order,
    const unsigned short* __restrict__ G1Tb, const unsigned short* __restrict__ M2T,
    float* __restrict__ out) {
    __shared__ unsigned short g1b[128 * 40];
    __shared__ unsigned short m2t[128 * 40];
    __shared__ int toks[TOKS_PER_BLK];

    const int t = threadIdx.x;
    const int base = blockIdx.x * TOKS_PER_BLK;
    const int p0 = order[base];
    if (p0 < 0) return;
    const int i2v = idx[p0 & TOK_MASK] % 100;

    {
        const int tk = t >> 1, half = t & 1;
        const int pk = order[base + tk];
        int4 v0 = {0, 0, 0, 0}, v1 = {0, 0, 0, 0};
        if (pk >= 0) {
            const int pair = pk >> 17;
            const int4* g = (const int4*)(G1Tb + pair * 32);
            v0 = g[half * 2];
            v1 = g[half * 2 + 1];
        }
        int4* d = (int4*)(g1b + tk * 40 + half * 16);
        d[0] = v0;
        d[1] = v1;
        if (t < TOKS_PER_BLK) toks[t] = order[base + t];
    }
    {
        const int j = t >> 1, half = t & 1;
        const int4* s = (const int4*)(M2T + i2v * 4096 + j * 32);
        int4* d = (int4*)(m2t + j * 40 + half * 16);
        d[0] = s[half * 2];
        d[1] = s[half * 2 + 1];
    }
    __syncthreads();

    const int wid  = t >> 6;
    const int lane = t & 63;
    const int ln15 = lane & 15;
    const int q8   = (lane >> 4) * 8;

    f32x4 acc[2][8];
#pragma unroll
    for (int a = 0; a < 2; ++a)
#pragma unroll
        for (int c = 0; c < 8; ++c) acc[a][c] = (f32x4){0.f, 0.f, 0.f, 0.f};

    bf16x8 af[2], bfr[8];
#pragma unroll
    for (int trr = 0; trr < 2; ++trr) {
        const int tok = (2 * wid + trr) * 16 + ln15;
        af[trr] = *(const bf16x8*)(g1b + tok * 40 + q8);
    }
#pragma unroll
    for (int tc = 0; tc < 8; ++tc) {
        const int j = tc * 16 + ln15;
        bfr[tc] = *(const bf16x8*)(m2t + j * 40 + q8);
    }
#pragma unroll
    for (int trr = 0; trr < 2; ++trr)
#pragma unroll
        for (int tc = 0; tc < 8; ++tc)
            acc[trr][tc] = __builtin_amdgcn_mfma_f32_16x16x32_bf16(
                af[trr], bfr[tc], acc[trr][tc], 0, 0, 0);

    const int rowq = (lane >> 4) * 4;
#pragma unroll
    for (int trr = 0; trr < 2; ++trr) {
#pragma unroll
        for (int reg = 0; reg < 4; ++reg) {
            const int tokr = (2 * wid + trr) * 16 + rowq + reg;
            const int pk = toks[tokr];
            if (pk >= 0) {
                const int n = pk & TOK_MASK;
                float* o = out + (size_t)n * 128 + ln15;
#pragma unroll
                for (int tc = 0; tc < 8; ++tc)
                    __builtin_nontemporal_store(acc[trr][tc][reg], &o[tc * 16]);
            }
        }
    }
}

// ---------------------------------------------------------------------------
// Fallback (round-4 verified) if ws too small.
// ---------------------------------------------------------------------------
__global__ void build_w(const float* __restrict__ c3, const float* __restrict__ c4,
                        const float* __restrict__ c5, float* __restrict__ W) {
    int t = blockIdx.x * blockDim.x + threadIdx.x;
    if (t >= 32 * 128) return;
    int r = t >> 7;
    int j = t & 127;
    int p  = j >> 5;
    int m1 = (j >> 2) & 7;
    int v  = j & 3;
    const float* c3row = c3 + (r * 4 + p) * 16;
    float acc = 0.f;
#pragma unroll
    for (int m2 = 0; m2 < 8; ++m2) {
        float t1 = 0.f;
#pragma unroll
        for (int q = 0; q < 16; ++q)
            t1 += c3row[q] * c4[q * 64 + m1 * 8 + m2];
        acc += t1 * c5[m2 * 4 + v];
    }
    W[r * 128 + j] = acc;
}

__global__ __launch_bounds__(256, 4) void tt_embed_fb(
    const int* __restrict__ idx, const float* __restrict__ c0,
    const float* __restrict__ c1, const float* __restrict__ c2,
    const float* __restrict__ Wg, float* __restrict__ out) {
    __shared__ float Wl[32 * 128];
    __shared__ float g2l[8][32];
    const int t = threadIdx.x;
    {
        const float4* Wg4 = (const float4*)Wg;
        float4* Wl4 = (float4*)Wl;
#pragma unroll
        for (int i = 0; i < 4; ++i) Wl4[t + i * 256] = Wg4[t + i * 256];
    }
    __syncthreads();
    const int tt = t >> 5, s = t & 31;
    const int blockBase = blockIdx.x * 32;
    for (int round = 0; round < 4; ++round) {
        const int n = blockBase + round * 8 + tt;
        const int iv = idx[n];
        const int i0 = iv / 10000;
        const int rem = iv - i0 * 10000;
        const int i1 = rem / 100;
        const int i2 = rem - i1 * 100;
        const float4* c0r4 = (const float4*)(c0 + i0 * 32);
        const float* c1p = c1 + i1 * 32 + s;
        float g1 = 0.f;
#pragma unroll
        for (int r4 = 0; r4 < 8; ++r4) {
            float4 a = c0r4[r4];
            g1 += a.x * c1p[(r4 * 4 + 0) * 3200];
            g1 += a.y * c1p[(r4 * 4 + 1) * 3200];
            g1 += a.z * c1p[(r4 * 4 + 2) * 3200];
            g1 += a.w * c1p[(r4 * 4 + 3) * 3200];
        }
        const float* c2p = c2 + i2 * 32 + s;
        float g2 = 0.f;
#pragma unroll
        for (int r = 0; r < 32; ++r) {
            float g1r = __shfl(g1, r, 32);
            g2 += g1r * c2p[r * 3200];
        }
        g2l[tt][s] = g2;
        __syncthreads();
        float4 acc = {0.f, 0.f, 0.f, 0.f};
        const float4* Wl4 = (const float4*)Wl;
#pragma unroll
        for (int r = 0; r < 32; ++r) {
            const float g = g2l[tt][r];
            const float4 w = Wl4[r * 32 + s];
            acc.x += g * w.x; acc.y += g * w.y; acc.z += g * w.z; acc.w += g * w.w;
        }
        float4* outp = (float4*)(out + (size_t)n * 128);
        outp[s] = acc;
        __syncthreads();
    }
}

// ---------------------------------------------------------------------------
extern "C" void kernel_launch(void* const* d_in, const int* in_sizes, int n_in,
                              void* d_out, int out_size, void* d_ws, size_t ws_size,
                              hipStream_t stream) {
    const int*   idx = (const int*)d_in[0];
    const float* c0  = (const float*)d_in[1];
    const float* c1  = (const float*)d_in[2];
    const float* c2  = (const float*)d_in[3];
    const float* c3  = (const float*)d_in[4];
    const float* c4  = (const float*)d_in[5];
    const float* c5  = (const float*)d_in[6];
    float* out = (float*)d_out;
    float* ws  = (float*)d_ws;

    if (ws_size >= WS_NEED) {
        unsigned short* M2T  = (unsigned short*)(ws + WS_M2T);
        unsigned short* G1Tb = (unsigned short*)(ws + WS_G1T);
        int* cntT  = (int*)(ws + WS_CNT);
        int* order = (int*)(ws + WS_ORD);

        hipLaunchKernelGGL(prep,  dim3(PREP_BLOCKS), dim3(256), 0, stream,
                           idx, c0, c1, c2, c3, c4, c5, M2T, G1Tb, cntT);
        hipLaunchKernelGGL(sort2, dim3(NCHUNK), dim3(256), 0, stream, idx, cntT, order);
        hipLaunchKernelGGL(tt_main, dim3(MAIN_TILES), dim3(256), 0, stream,
                           idx, order, G1Tb, M2T, out);
    } else {
        float* W = ws;
        hipLaunchKernelGGL(build_w, dim3(16), dim3(256), 0, stream, c3, c4, c5, W);
        hipLaunchKernelGGL(tt_embed_fb, dim3(N_TOKENS / 32), dim3(256), 0, stream,
                           idx, c0, c1, c2, W, out);
    }
}

// Round 23
// 25.563 us; speedup vs baseline: 1.1121x; 1.1121x over previous
//
#include <hip/hip_runtime.h>

#define N_TOKENS   65536
#define TOKS_PER_BLK 128
#define MAIN_TILES (N_TOKENS / TOKS_PER_BLK + 100)    // 612
#define ORD_SIZE    (MAIN_TILES * TOKS_PER_BLK)       // 78336
#define NB_M2   400
#define NB_G1T  1250
#define NB_HIST 64
#define PREP_BLOCKS (NB_M2 + NB_G1T + NB_HIST)        // 1714
#define TOK_MASK 0x1FFFF                               // low 17 bits = token id

// ---- ws layout (float offsets) ----
#define WS_M2T  0                          // 100*4096 bf16 = 204800 floats
#define WS_G1T  204800                     // 10000*32 bf16 = 160000 floats
#define WS_CNT  364800                     // cntT[128][64] ints = 8192
#define WS_ORD  372992                     // ORD_SIZE ints
#define WS_NEED ((size_t)(372992 + ORD_SIZE) * 4)     // ~1.8 MB

typedef __attribute__((ext_vector_type(8))) short bf16x8;
typedef __attribute__((ext_vector_type(4))) float f32x4;

__device__ __forceinline__ unsigned short f2bf(float x) {
    union { float f; unsigned u; } v; v.f = x;
    unsigned r = v.u + 0x7FFF + ((v.u >> 16) & 1);   // RNE
    return (unsigned short)(r >> 16);
}

// ---------------------------------------------------------------------------
// K1 "prep" — verified (~5.9 us): M2 400-way split / G1T / transposed hist.
// ---------------------------------------------------------------------------
__global__ __launch_bounds__(256) void prep(
    const int* __restrict__ idx,
    const float* __restrict__ c0, const float* __restrict__ c1,
    const float* __restrict__ c2, const float* __restrict__ c3,
    const float* __restrict__ c4, const float* __restrict__ c5,
    unsigned short* __restrict__ M2T, unsigned short* __restrict__ G1Tb,
    int* __restrict__ cntT) {
    __shared__ float smem[5200];
    const int b = blockIdx.x, t = threadIdx.x;

    if (b < NB_M2) {
        const int i2 = b >> 2;
        const int p  = b & 3;
        float* c4l = smem;
        float* c5l = smem + 1024;
        float* t45 = smem + 1056;
        float* c3p = smem + 1568;
        float* Wl  = smem + 2080;
        float* c2l = smem + 3104;
        *(float4*)(c4l + t * 4) = *(const float4*)(c4 + t * 4);
        if (t < 8) *(float4*)(c5l + t * 4) = *(const float4*)(c5 + t * 4);
        if (t < 128) {
            const int r = t >> 2, q4 = (t & 3) * 4;
            *(float4*)(c3p + r * 16 + q4) = *(const float4*)(c3 + (r * 4 + p) * 16 + q4);
        }
        {
            const int r = t >> 3, s4 = (t & 7) * 4;
            const float4 v = *(const float4*)(c2 + r * 3200 + i2 * 32 + s4);
            c2l[r * 33 + s4 + 0] = v.x;
            c2l[r * 33 + s4 + 1] = v.y;
            c2l[r * 33 + s4 + 2] = v.z;
            c2l[r * 33 + s4 + 3] = v.w;
        }
        __syncthreads();
#pragma unroll
        for (int k = 0; k < 2; ++k) {      // T45[q][u]
            const int e = t + k * 256;
            const int q = e >> 5, u = e & 31;
            const int m1 = u >> 2, v = u & 3;
            float acc = 0.f;
#pragma unroll
            for (int m2 = 0; m2 < 8; ++m2)
                acc = fmaf(c4l[q * 64 + m1 * 8 + m2], c5l[m2 * 4 + v], acc);
            t45[e] = acc;
        }
        __syncthreads();
#pragma unroll
        for (int k = 0; k < 4; ++k) {      // Wl[s][jl]
            const int e = t + k * 256;
            const int s = e >> 5, jl = e & 31;
            float acc = 0.f;
#pragma unroll
            for (int q = 0; q < 16; ++q)
                acc = fmaf(c3p[s * 16 + q], t45[q * 32 + jl], acc);
            Wl[e] = acc;
        }
        __syncthreads();
#pragma unroll
        for (int k = 0; k < 4; ++k) {      // M2T[i2][(p*32+jl)*32+r]
            const int e = t + k * 256;
            const int jl = e >> 5, r = e & 31;
            float acc = 0.f;
#pragma unroll
            for (int s = 0; s < 32; ++s)
                acc = fmaf(c2l[r * 33 + s], Wl[s * 32 + jl], acc);
            M2T[i2 * 4096 + p * 1024 + e] = f2bf(acc);
        }
    } else if (b < NB_M2 + NB_G1T) {
        const int pair = (b - NB_M2) * 8 + (t >> 5);
        const int s = t & 31;
        const int i0 = pair / 100;
        const int i1 = pair - i0 * 100;
        const float4* a4 = (const float4*)(c0 + i0 * 32);
        const float* c1p = c1 + i1 * 32 + s;
        float acc = 0.f;
#pragma unroll
        for (int r4 = 0; r4 < 8; ++r4) {
            const float4 a = a4[r4];
            acc = fmaf(a.x, c1p[(r4 * 4 + 0) * 3200], acc);
            acc = fmaf(a.y, c1p[(r4 * 4 + 1) * 3200], acc);
            acc = fmaf(a.z, c1p[(r4 * 4 + 2) * 3200], acc);
            acc = fmaf(a.w, c1p[(r4 * 4 + 3) * 3200], acc);
        }
        G1Tb[pair * 32 + s] = f2bf(acc);
    } else {
        const int hb = b - (NB_M2 + NB_G1T);
        int* lh = (int*)smem;
        if (t < 128) lh[t] = 0;
        __syncthreads();
#pragma unroll
        for (int k = 0; k < 4; ++k) {
            const int n = hb * 1024 + k * 256 + t;
            atomicAdd(&lh[idx[n] % 100], 1);
        }
        __syncthreads();
        if (t < 128) cntT[t * 64 + hb] = lh[t];
    }
}

// ---------------------------------------------------------------------------
// K2 "sort2" — verified (~3.7 us): 64 blocks; packed (pair<<17)|token.
// ---------------------------------------------------------------------------
__global__ __launch_bounds__(256) void sort2(const int* __restrict__ idx,
                                             const int* __restrict__ cntT,
                                             int* __restrict__ order) {
    __shared__ int totals[100];
    __shared__ int offsj[100];
    __shared__ int sb[101];
    __shared__ int lhj[100];
    const int j = blockIdx.x, t = threadIdx.x;
    if (t < 100) {
        lhj[t] = 0;
        const int4* row = (const int4*)(cntT + t * 64);
        int tot = 0, off = 0;
#pragma unroll
        for (int i = 0; i < 16; ++i) {
            const int4 v = row[i];
            const int cb = i * 4;
            tot += v.x + v.y + v.z + v.w;
            if (cb + 0 < j) off += v.x;
            if (cb + 1 < j) off += v.y;
            if (cb + 2 < j) off += v.z;
            if (cb + 3 < j) off += v.w;
        }
        totals[t] = tot;
        offsj[t] = off;
    }
    __syncthreads();
    if (t < 64) {
        const int e0 = 2 * t, e1 = 2 * t + 1;
        const int p0 = (e0 < 100) ? ((totals[e0] + 127) & ~127) : 0;
        const int p1 = (e1 < 100) ? ((totals[e1] + 127) & ~127) : 0;
        const int pair = p0 + p1;
        int incl = pair;
#pragma unroll
        for (int d = 1; d < 64; d <<= 1) {
            const int v = __shfl_up(incl, d, 64);
            if (t >= d) incl += v;
        }
        const int base = incl - pair;
        if (e0 < 100) sb[e0] = base;
        if (e1 < 100) sb[e1] = base + p0;
        if (t == 63) sb[100] = incl;
    }
    __syncthreads();
    int bkt[4], rnk[4], pkd[4];
#pragma unroll
    for (int k = 0; k < 4; ++k) {
        const int n = j * 1024 + k * 256 + t;
        const int iv = idx[n];
        const int bb = iv % 100;
        bkt[k] = bb;
        pkd[k] = ((iv / 100) << 17) | n;          // pack pair + token
        rnk[k] = atomicAdd(&lhj[bb], 1);
    }
#pragma unroll
    for (int k = 0; k < 4; ++k)
        order[sb[bkt[k]] + offsj[bkt[k]] + rnk[k]] = pkd[k];
    for (int bb = j; bb < 100; bb += 64) {
        const int tot = totals[bb];
        const int pt = (tot + 127) & ~127;
        for (int i = tot + t; i < pt; i += 256) order[sb[bb] + i] = -1;
    }
    {
        const int gt = sb[100];
        for (int i = gt + j * 256 + t; i < ORD_SIZE; i += 64 * 256) order[i] = -1;
    }
}

// ---------------------------------------------------------------------------
// K3 "tt_main" — verified (~7.8 us): MFMA + NT stores + packed gather.
// ---------------------------------------------------------------------------
__global__ __launch_bounds__(256) void tt_main(
    const int* __restrict__ idx, const int* __restrict__ order,
    const unsigned short* __restrict__ G1Tb, const unsigned short* __restrict__ M2T,
    float* __restrict__ out) {
    __shared__ unsigned short g1b[128 * 40];
    __shared__ unsigned short m2t[128 * 40];
    __shared__ int toks[TOKS_PER_BLK];

    const int t = threadIdx.x;
    const int base = blockIdx.x * TOKS_PER_BLK;
    const int p0 = order[base];
    if (p0 < 0) return;
    const int i2v = idx[p0 & TOK_MASK] % 100;

    {
        const int tk = t >> 1, half = t & 1;
        const int pk = order[base + tk];
        int4 v0 = {0, 0, 0, 0}, v1 = {0, 0, 0, 0};
        if (pk >= 0) {
            const int pair = pk >> 17;
            const int4* g = (const int4*)(G1Tb + pair * 32);
            v0 = g[half * 2];
            v1 = g[half * 2 + 1];
        }
        int4* d = (int4*)(g1b + tk * 40 + half * 16);
        d[0] = v0;
        d[1] = v1;
        if (t < TOKS_PER_BLK) toks[t] = order[base + t];
    }
    {
        const int j = t >> 1, half = t & 1;
        const int4* s = (const int4*)(M2T + i2v * 4096 + j * 32);
        int4* d = (int4*)(m2t + j * 40 + half * 16);
        d[0] = s[half * 2];
        d[1] = s[half * 2 + 1];
    }
    __syncthreads();

    const int wid  = t >> 6;
    const int lane = t & 63;
    const int ln15 = lane & 15;
    const int q8   = (lane >> 4) * 8;

    f32x4 acc[2][8];
#pragma unroll
    for (int a = 0; a < 2; ++a)
#pragma unroll
        for (int c = 0; c < 8; ++c) acc[a][c] = (f32x4){0.f, 0.f, 0.f, 0.f};

    bf16x8 af[2], bfr[8];
#pragma unroll
    for (int trr = 0; trr < 2; ++trr) {
        const int tok = (2 * wid + trr) * 16 + ln15;
        af[trr] = *(const bf16x8*)(g1b + tok * 40 + q8);
    }
#pragma unroll
    for (int tc = 0; tc < 8; ++tc) {
        const int j = tc * 16 + ln15;
        bfr[tc] = *(const bf16x8*)(m2t + j * 40 + q8);
    }
#pragma unroll
    for (int trr = 0; trr < 2; ++trr)
#pragma unroll
        for (int tc = 0; tc < 8; ++tc)
            acc[trr][tc] = __builtin_amdgcn_mfma_f32_16x16x32_bf16(
                af[trr], bfr[tc], acc[trr][tc], 0, 0, 0);

    const int rowq = (lane >> 4) * 4;
#pragma unroll
    for (int trr = 0; trr < 2; ++trr) {
#pragma unroll
        for (int reg = 0; reg < 4; ++reg) {
            const int tokr = (2 * wid + trr) * 16 + rowq + reg;
            const int pk = toks[tokr];
            if (pk >= 0) {
                const int n = pk & TOK_MASK;
                float* o = out + (size_t)n * 128 + ln15;
#pragma unroll
                for (int tc = 0; tc < 8; ++tc)
                    __builtin_nontemporal_store(acc[trr][tc][reg], &o[tc * 16]);
            }
        }
    }
}

// ---------------------------------------------------------------------------
// Fallback (round-4 verified) if ws too small.
// ---------------------------------------------------------------------------
__global__ void build_w(const float* __restrict__ c3, const float* __restrict__ c4,
                        const float* __restrict__ c5, float* __restrict__ W) {
    int t = blockIdx.x * blockDim.x + threadIdx.x;
    if (t >= 32 * 128) return;
    int r = t >> 7;
    int j = t & 127;
    int p  = j >> 5;
    int m1 = (j >> 2) & 7;
    int v  = j & 3;
    const float* c3row = c3 + (r * 4 + p) * 16;
    float acc = 0.f;
#pragma unroll
    for (int m2 = 0; m2 < 8; ++m2) {
        float t1 = 0.f;
#pragma unroll
        for (int q = 0; q < 16; ++q)
            t1 += c3row[q] * c4[q * 64 + m1 * 8 + m2];
        acc += t1 * c5[m2 * 4 + v];
    }
    W[r * 128 + j] = acc;
}

__global__ __launch_bounds__(256, 4) void tt_embed_fb(
    const int* __restrict__ idx, const float* __restrict__ c0,
    const float* __restrict__ c1, const float* __restrict__ c2,
    const float* __restrict__ Wg, float* __restrict__ out) {
    __shared__ float Wl[32 * 128];
    __shared__ float g2l[8][32];
    const int t = threadIdx.x;
    {
        const float4* Wg4 = (const float4*)Wg;
        float4* Wl4 = (float4*)Wl;
#pragma unroll
        for (int i = 0; i < 4; ++i) Wl4[t + i * 256] = Wg4[t + i * 256];
    }
    __syncthreads();
    const int tt = t >> 5, s = t & 31;
    const int blockBase = blockIdx.x * 32;
    for (int round = 0; round < 4; ++round) {
        const int n = blockBase + round * 8 + tt;
        const int iv = idx[n];
        const int i0 = iv / 10000;
        const int rem = iv - i0 * 10000;
        const int i1 = rem / 100;
        const int i2 = rem - i1 * 100;
        const float4* c0r4 = (const float4*)(c0 + i0 * 32);
        const float* c1p = c1 + i1 * 32 + s;
        float g1 = 0.f;
#pragma unroll
        for (int r4 = 0; r4 < 8; ++r4) {
            float4 a = c0r4[r4];
            g1 += a.x * c1p[(r4 * 4 + 0) * 3200];
            g1 += a.y * c1p[(r4 * 4 + 1) * 3200];
            g1 += a.z * c1p[(r4 * 4 + 2) * 3200];
            g1 += a.w * c1p[(r4 * 4 + 3) * 3200];
        }
        const float* c2p = c2 + i2 * 32 + s;
        float g2 = 0.f;
#pragma unroll
        for (int r = 0; r < 32; ++r) {
            float g1r = __shfl(g1, r, 32);
            g2 += g1r * c2p[r * 3200];
        }
        g2l[tt][s] = g2;
        __syncthreads();
        float4 acc = {0.f, 0.f, 0.f, 0.f};
        const float4* Wl4 = (const float4*)Wl;
#pragma unroll
        for (int r = 0; r < 32; ++r) {
            const float g = g2l[tt][r];
            const float4 w = Wl4[r * 32 + s];
            acc.x += g * w.x; acc.y += g * w.y; acc.z += g * w.z; acc.w += g * w.w;
        }
        float4* outp = (float4*)(out + (size_t)n * 128);
        outp[s] = acc;
        __syncthreads();
    }
}

// ---------------------------------------------------------------------------
extern "C" void kernel_launch(void* const* d_in, const int* in_sizes, int n_in,
                              void* d_out, int out_size, void* d_ws, size_t ws_size,
                              hipStream_t stream) {
    const int*   idx = (const int*)d_in[0];
    const float* c0  = (const float*)d_in[1];
    const float* c1  = (const float*)d_in[2];
    const float* c2  = (const float*)d_in[3];
    const float* c3  = (const float*)d_in[4];
    const float* c4  = (const float*)d_in[5];
    const float* c5  = (const float*)d_in[6];
    float* out = (float*)d_out;
    float* ws  = (float*)d_ws;

    if (ws_size >= WS_NEED) {
        unsigned short* M2T  = (unsigned short*)(ws + WS_M2T);
        unsigned short* G1Tb = (unsigned short*)(ws + WS_G1T);
        int* cntT  = (int*)(ws + WS_CNT);
        int* order = (int*)(ws + WS_ORD);

        hipLaunchKernelGGL(prep,  dim3(PREP_BLOCKS), dim3(256), 0, stream,
                           idx, c0, c1, c2, c3, c4, c5, M2T, G1Tb, cntT);
        hipLaunchKernelGGL(sort2, dim3(NB_HIST), dim3(256), 0, stream, idx, cntT, order);
        hipLaunchKernelGGL(tt_main, dim3(MAIN_TILES), dim3(256), 0, stream,
                           idx, order, G1Tb, M2T, out);
    } else {
        float* W = ws;
        hipLaunchKernelGGL(build_w, dim3(16), dim3(256), 0, stream, c3, c4, c5, W);
        hipLaunchKernelGGL(tt_embed_fb, dim3(N_TOKENS / 32), dim3(256), 0, stream,
                           idx, c0, c1, c2, W, out);
    }
}